// Round 18
// baseline (530.317 us; speedup 1.0000x reference)
//
#include <hip/hip_runtime.h>

typedef _Float16 f16;
typedef _Float16 f16x2 __attribute__((ext_vector_type(2)));
typedef _Float16 f16x8 __attribute__((ext_vector_type(8)));
typedef float f32x4 __attribute__((ext_vector_type(4)));

#define MFMA16(a,b,c) __builtin_amdgcn_mfma_f32_16x16x32_f16((a),(b),(c),0,0,0)

// ---------------- index dtype detection (parallel) ----------------
__global__ void k_detect(const long long* ei, int n_nodes, int* flag) {
    long long v = ei[threadIdx.x];
    int bad = (v < 0 || v >= n_nodes);
    unsigned long long m = __ballot(bad);
    if (threadIdx.x == 0) *flag = (m == 0ULL);   // 1 => int64, 0 => int32
}

// histogram only (deg pre-zeroed)
__global__ void k_hist(const void* ei, int E, const int* __restrict__ flag,
                       int* __restrict__ deg) {
    int e = blockIdx.x * 256 + threadIdx.x;
    if (e >= E) return;
    int d;
    if (*flag) d = (int)((const long long*)ei)[(size_t)E + e];
    else       d = ((const int*)ei)[(size_t)E + e];
    atomicAdd(&deg[d], 1);
}

// ---------------- device helper: SAGE W frag ----------------
__device__ __forceinline__ void wfrag_body(const float* Wa, const float* Wb,
                                           f16* dst, int t) {
    int l = t & 63;
    int s = t >> 9;
    int k0 = s * 32 + (l >> 4) * 8;
    int j = ((t >> 6) & 7) * 16 + (l & 15);
    f16x8 h;
    #pragma unroll
    for (int e = 0; e < 8; e++) {
        int k = k0 + e;
        float v = (k < 128) ? Wa[k * 128 + j] : Wb[(k - 128) * 128 + j];
        h[e] = (f16)v;
    }
    *(f16x8*)(dst + (size_t)t * 8) = h;
}

// ---------------- fused prep: x2h + w1f + w2f + zwf + wef ----------------
__global__ void k_prep(const float* __restrict__ x,
                       const float* __restrict__ Wl1, const float* __restrict__ Wr1,
                       const float* __restrict__ Wl2, const float* __restrict__ Wr2,
                       const float* __restrict__ Wm1,
                       f16* __restrict__ xh, f16* __restrict__ w1f, f16* __restrict__ w2f,
                       f16* __restrict__ zwf, f16* __restrict__ wef, int N) {
    const int xb = (N * 16 + 255) / 256;
    int b = blockIdx.x;
    if (b < xb) {
        int i = (b * 256 + threadIdx.x) * 8;
        if (i >= N * 128) return;
        float4 a = *(const float4*)(x + i);
        float4 c = *(const float4*)(x + i + 4);
        f16x8 h;
        h[0] = (f16)a.x; h[1] = (f16)a.y; h[2] = (f16)a.z; h[3] = (f16)a.w;
        h[4] = (f16)c.x; h[5] = (f16)c.y; h[6] = (f16)c.z; h[7] = (f16)c.w;
        *(f16x8*)(xh + i) = h;
        return;
    }
    b -= xb;
    if (b < 16) { wfrag_body(Wl1, Wr1, w1f, b * 256 + threadIdx.x); return; }
    if (b < 32) { wfrag_body(Wl2, Wr2, w2f, (b - 16) * 256 + threadIdx.x); return; }
    if (b < 48) {                       // zwf
        int t = (b - 32) * 256 + threadIdx.x;
        int lane = t & 63, c = (t >> 6) & 15, s = t >> 10;
        int k0 = s * 32 + (lane >> 4) * 8;
        int j = c * 16 + (lane & 15);
        f16x8 h;
        #pragma unroll
        for (int e = 0; e < 8; e++) {
            int k = k0 + e;
            float v = (j < 128) ? Wm1[k * 128 + j] : Wm1[(128 + k) * 128 + (j - 128)];
            h[e] = (f16)v;
        }
        *(f16x8*)(zwf + (size_t)t * 8) = h;
        return;
    }
    {                                   // wef (paired-column order)
        int t = (b - 48) * 256 + threadIdx.x;
        if (t >= 8 * 64) return;
        int lane = t & 63, ct = t >> 6;
        int k0 = (lane >> 4) * 8;
        int j = (ct >> 1) * 32 + 2 * (lane & 15) + (ct & 1);
        f16x8 h;
        #pragma unroll
        for (int e = 0; e < 8; e++) {
            int k = k0 + e;
            h[e] = (k < 16) ? (f16)Wm1[(256 + k) * 128 + j] : (f16)0.0f;
        }
        *(f16x8*)(wef + (size_t)t * 8) = h;
    }
}

// ---------------- CSR build ----------------
__global__ void k_bsum(const int* __restrict__ deg, int n, int* __restrict__ bsum) {
    __shared__ int ws[4];
    const int tid = threadIdx.x;
    int i = blockIdx.x * 1024 + tid * 4;
    int s = 0;
    if (i + 3 < n) {
        int4 d = *(const int4*)(deg + i);
        s = d.x + d.y + d.z + d.w;
    } else {
        #pragma unroll
        for (int j = 0; j < 4; j++) if (i + j < n) s += deg[i + j];
    }
    #pragma unroll
    for (int m = 1; m < 64; m <<= 1) s += __shfl_xor(s, m, 64);
    if ((tid & 63) == 0) ws[tid >> 6] = s;
    __syncthreads();
    if (tid == 0) bsum[blockIdx.x] = ws[0] + ws[1] + ws[2] + ws[3];
}

__global__ void k_bscan(int* __restrict__ bsum, int nb, int* __restrict__ rowptr_n) {
    __shared__ int wsum[4];
    const int tid = threadIdx.x, lane = tid & 63, wid = tid >> 6;
    int v = (tid < nb) ? bsum[tid] : 0;
    int inc = v;
    #pragma unroll
    for (int off = 1; off < 64; off <<= 1) {
        int u = __shfl_up(inc, off, 64);
        if (lane >= off) inc += u;
    }
    if (lane == 63) wsum[wid] = inc;
    __syncthreads();
    int woff = 0;
    for (int j = 0; j < wid; j++) woff += wsum[j];
    int excl = woff + inc - v;
    if (tid < nb) bsum[tid] = excl;
    if (tid == nb - 1) rowptr_n[0] = excl + v;
}

__global__ void k_rowptr(const int* __restrict__ deg, int n, const int* __restrict__ boff,
                         int* __restrict__ rowptr, int* __restrict__ cursor) {
    __shared__ int wsum[4];
    const int tid = threadIdx.x, lane = tid & 63, wid = tid >> 6;
    int i = blockIdx.x * 1024 + tid * 4;
    int d0 = 0, d1 = 0, d2 = 0, d3 = 0;
    if (i + 3 < n) {
        int4 d = *(const int4*)(deg + i);
        d0 = d.x; d1 = d.y; d2 = d.z; d3 = d.w;
    } else {
        if (i     < n) d0 = deg[i];
        if (i + 1 < n) d1 = deg[i + 1];
        if (i + 2 < n) d2 = deg[i + 2];
        if (i + 3 < n) d3 = deg[i + 3];
    }
    int s = d0 + d1 + d2 + d3;
    int inc = s;
    #pragma unroll
    for (int off = 1; off < 64; off <<= 1) {
        int u = __shfl_up(inc, off, 64);
        if (lane >= off) inc += u;
    }
    if (lane == 63) wsum[wid] = inc;
    __syncthreads();
    int woff = 0;
    for (int j = 0; j < wid; j++) woff += wsum[j];
    int excl = boff[blockIdx.x] + woff + inc - s;
    int e1 = excl + d0, e2 = e1 + d1, e3 = e2 + d2;
    if (i     < n) { rowptr[i]     = excl; cursor[i]     = excl; }
    if (i + 1 < n) { rowptr[i + 1] = e1;   cursor[i + 1] = e1; }
    if (i + 2 < n) { rowptr[i + 2] = e2;   cursor[i + 2] = e2; }
    if (i + 3 < n) { rowptr[i + 3] = e3;   cursor[i + 3] = e3; }
}

// dstp[p] = node owning position p — SEQUENTIAL sweep (one thread per node)
__global__ void k_dfill(const int* __restrict__ rowptr, int N, int* __restrict__ dstp) {
    int n = blockIdx.x * 256 + threadIdx.x;
    if (n >= N) return;
    const int s0 = rowptr[n], s1 = rowptr[n + 1];
    for (int p = s0; p < s1; ++p) dstp[p] = n;
}

// scatter: ONE random 8B stream pk2[p]=(src,eid); pos[e]=p sequential
__global__ void k_scatter(const void* ei, int E, const int* __restrict__ flag,
                          int* __restrict__ cursor, int2* __restrict__ pk2,
                          int* __restrict__ pos) {
    int e = blockIdx.x * 256 + threadIdx.x;
    if (e >= E) return;
    int s, d;
    if (*flag) {
        const long long* p = (const long long*)ei;
        s = (int)p[e];
        d = (int)p[(size_t)E + e];
    } else {
        const int* p = (const int*)ei;
        s = p[e];
        d = p[(size_t)E + e];
    }
    int p2 = atomicAdd(&cursor[d], 1);
    pk2[p2] = make_int2(s, e);           // single random write stream
    pos[e] = p2;                         // sequential
}

// ---------------- fused layer kernel (neighbor index from pk2.x) ----------------
#define AP 136
template<int DO_Z>
__global__ __launch_bounds__(256, DO_Z ? 4 : 5) void k_fuse(
    const f16* __restrict__ tab,
    const int* __restrict__ rowptr, const int2* __restrict__ pk2,
    const f16* __restrict__ Wf, const float* __restrict__ bias,
    const f16* __restrict__ zwf, const float* __restrict__ bm1,
    f16* __restrict__ out, int n_rows) {
    __shared__ __align__(16) f16 sA[64 * AP];
    const int tid = threadIdx.x, lane = tid & 63, w = tid >> 6;
    const int l15 = lane & 15, g = lane >> 4;
    const int base = blockIdx.x * 64;

    const int g16 = tid >> 4, c = tid & 15;
    #pragma unroll
    for (int rep = 0; rep < 4; rep++) {
        const int node = base + rep * 16 + g16;
        float acc[8] = {0.f, 0.f, 0.f, 0.f, 0.f, 0.f, 0.f, 0.f};
        int d = 1;
        if (node < n_rows) {
            const int s0 = rowptr[node], s1 = rowptr[node + 1];
            int k = s0;
            for (; k + 3 < s1; k += 4) {
                const int n0 = pk2[k].x, n1 = pk2[k + 1].x, n2 = pk2[k + 2].x, n3 = pk2[k + 3].x;
                f16x8 v0 = *(const f16x8*)(tab + (size_t)n0 * 128 + c * 8);
                f16x8 v1 = *(const f16x8*)(tab + (size_t)n1 * 128 + c * 8);
                f16x8 v2 = *(const f16x8*)(tab + (size_t)n2 * 128 + c * 8);
                f16x8 v3 = *(const f16x8*)(tab + (size_t)n3 * 128 + c * 8);
                #pragma unroll
                for (int j = 0; j < 8; j++)
                    acc[j] += ((float)v0[j] + (float)v1[j]) + ((float)v2[j] + (float)v3[j]);
            }
            for (; k < s1; ++k) {
                const int n0 = pk2[k].x;
                f16x8 v0 = *(const f16x8*)(tab + (size_t)n0 * 128 + c * 8);
                #pragma unroll
                for (int j = 0; j < 8; j++) acc[j] += (float)v0[j];
            }
            d = s1 - s0; if (d < 1) d = 1;
        }
        const float inv = 1.f / (float)d;
        f16x8 r;
        #pragma unroll
        for (int j = 0; j < 8; j++) r[j] = (f16)(acc[j] * inv);
        *(f16x8*)&sA[(rep * 16 + g16) * AP + c * 8] = r;
    }
    __syncthreads();

    const int c0 = (2 * w) * 16 + l15, c1 = c0 + 16;
    const float b0 = bias[c0], b1 = bias[c1];
    f32x4 acc[4][2];
    #pragma unroll
    for (int t = 0; t < 4; t++) {
        acc[t][0] = f32x4{b0, b0, b0, b0};
        acc[t][1] = f32x4{b1, b1, b1, b1};
    }
    #pragma unroll
    for (int s = 0; s < 8; s++) {
        f16x8 bf0 = *(const f16x8*)&Wf[((size_t)(s * 8 + 2 * w    ) * 64 + lane) * 8];
        f16x8 bf1 = *(const f16x8*)&Wf[((size_t)(s * 8 + 2 * w + 1) * 64 + lane) * 8];
        const int koff = (s & 3) * 32 + g * 8;
        #pragma unroll
        for (int t = 0; t < 4; t++) {
            f16x8 a;
            if (s < 4) {
                a = *(const f16x8*)&sA[(t * 16 + l15) * AP + koff];
            } else {
                int row = base + t * 16 + l15;
                if (row >= n_rows) row = n_rows - 1;
                a = *(const f16x8*)(tab + (size_t)row * 128 + koff);
            }
            acc[t][0] = MFMA16(a, bf0, acc[t][0]);
            acc[t][1] = MFMA16(a, bf1, acc[t][1]);
        }
    }

    if (DO_Z == 0) {
        #pragma unroll
        for (int t = 0; t < 4; t++) {
            #pragma unroll
            for (int i = 0; i < 4; i++) {
                int row = base + t * 16 + g * 4 + i;
                if (row < n_rows) {
                    float v0 = acc[t][0][i]; v0 = v0 > 0.f ? v0 : 0.f;
                    float v1 = acc[t][1][i]; v1 = v1 > 0.f ? v1 : 0.f;
                    out[(size_t)row * 128 + c0] = (f16)v0;
                    out[(size_t)row * 128 + c1] = (f16)v1;
                }
            }
        }
    } else {
        __syncthreads();
        #pragma unroll
        for (int t = 0; t < 4; t++) {
            #pragma unroll
            for (int i = 0; i < 4; i++) {
                const int rl = t * 16 + g * 4 + i;
                float v0 = acc[t][0][i]; v0 = v0 > 0.f ? v0 : 0.f;
                float v1 = acc[t][1][i]; v1 = v1 > 0.f ? v1 : 0.f;
                sA[rl * AP + c0] = (f16)v0;
                sA[rl * AP + c1] = (f16)v1;
            }
        }
        __syncthreads();
        #pragma unroll
        for (int half = 0; half < 2; half++) {
            const int j0 = (4 * w + 2 * half) * 16 + l15, j1 = j0 + 16;
            const float zb0 = (j0 >= 128) ? bm1[j0 - 128] : 0.0f;
            const float zb1 = (j1 >= 128) ? bm1[j1 - 128] : 0.0f;
            f32x4 zacc[4][2];
            #pragma unroll
            for (int t = 0; t < 4; t++) {
                zacc[t][0] = f32x4{zb0, zb0, zb0, zb0};
                zacc[t][1] = f32x4{zb1, zb1, zb1, zb1};
            }
            #pragma unroll
            for (int s = 0; s < 4; s++) {
                f16x8 wf0 = *(const f16x8*)&zwf[((size_t)(s * 16 + 4 * w + 2 * half    ) * 64 + lane) * 8];
                f16x8 wf1 = *(const f16x8*)&zwf[((size_t)(s * 16 + 4 * w + 2 * half + 1) * 64 + lane) * 8];
                const int koff = s * 32 + g * 8;
                #pragma unroll
                for (int t = 0; t < 4; t++) {
                    f16x8 a = *(const f16x8*)&sA[(t * 16 + l15) * AP + koff];
                    zacc[t][0] = MFMA16(a, wf0, zacc[t][0]);
                    zacc[t][1] = MFMA16(a, wf1, zacc[t][1]);
                }
            }
            #pragma unroll
            for (int t = 0; t < 4; t++) {
                #pragma unroll
                for (int i = 0; i < 4; i++) {
                    int row = base + t * 16 + g * 4 + i;
                    if (row < n_rows) {
                        out[(size_t)row * 256 + j0] = (f16)zacc[t][0][i];
                        out[(size_t)row * 256 + j1] = (f16)zacc[t][1][i];
                    }
                }
            }
        }
    }
}

// ---------------- edge kernel: CSR-position order, pk2+dstp loads, sequential tmp ----------------
#define ZP3 136
__global__ __launch_bounds__(256, 4) void k_edge3(
    const f16* __restrict__ z, const float* __restrict__ ea,
    const int2* __restrict__ pk2, const int* __restrict__ dstp,
    const f16* __restrict__ wef, const float* __restrict__ Wm2,
    const float* __restrict__ bm2, float* __restrict__ tmp,
    int E, int iters, int nwaves) {
    __shared__ __align__(16) f16 sZ[4][16 * ZP3];   // 4352 B per wave
    const int tid = threadIdx.x, lane = tid & 63, w = tid >> 6;
    const int l15 = lane & 15, g = lane >> 4;
    const int te = lane >> 2, sq = lane & 3;        // 4-lane team per edge
    const int gw = blockIdx.x * 4 + w;

    f16x8 be[8];
    #pragma unroll
    for (int cc = 0; cc < 8; cc++)
        be[cc] = *(const f16x8*)(wef + ((size_t)(cc * 64 + lane)) * 8);
    float2 w2p[4];
    #pragma unroll
    for (int pg = 0; pg < 4; pg++)
        w2p[pg] = *(const float2*)&Wm2[pg * 32 + 2 * l15];
    const float bv = bm2[0];

    f16* myZ = &sZ[w][0];

    f16x8 zs[4], zd[4];
    f16x8 a_cur, a_next;

    auto stage_load = [&](int pbase, f16x8* zsv, f16x8* zdv, f16x8& av) {
        int pr = pbase + te; if (pr > E - 1) pr = E - 1;
        const int is = pk2[pr].x;
        const int id = dstp[pr];                     // sequential read
        const f16* ps = z + (size_t)is * 256 + sq * 8;
        const f16* pd = z + (size_t)id * 256 + 128 + sq * 8;
        #pragma unroll
        for (int i = 0; i < 4; i++) {
            zsv[i] = *(const f16x8*)(ps + i * 32);   // line-coherent 16B chunks
            zdv[i] = *(const f16x8*)(pd + i * 32);
        }
        int pe = pbase + l15; if (pe > E - 1) pe = E - 1;
        f16x8 av_ = {};
        if (g < 2) {
            const int ee2 = pk2[pe].y;
            float4 e0 = *(const float4*)(ea + (size_t)ee2 * 16 + g * 8);
            float4 e1 = *(const float4*)(ea + (size_t)ee2 * 16 + g * 8 + 4);
            av_[0] = (f16)e0.x; av_[1] = (f16)e0.y; av_[2] = (f16)e0.z; av_[3] = (f16)e0.w;
            av_[4] = (f16)e1.x; av_[5] = (f16)e1.y; av_[6] = (f16)e1.z; av_[7] = (f16)e1.w;
        }
        av = av_;
    };
    auto stage_write = [&]() {
        f16* zp = myZ + te * ZP3 + sq * 8;
        #pragma unroll
        for (int i = 0; i < 4; i++) {
            f16x8 v = zs[i] + zd[i];            // v_pk_add_f16
            *(f16x8*)(zp + i * 32) = v;
        }
    };

    stage_load(gw * 16, zs, zd, a_cur);
    stage_write();

    for (int it = 0; it < iters; ++it) {
        const int pbase = (gw + it * nwaves) * 16;
        if (pbase >= E) break;
        const int nxt = (gw + (it + 1) * nwaves) * 16;
        const bool has_next = (it + 1 < iters) && (nxt < E);
        if (has_next) stage_load(nxt, zs, zd, a_next);

        f32x4 acc[8];
        #pragma unroll
        for (int cc = 0; cc < 8; cc++) acc[cc] = f32x4{0.f, 0.f, 0.f, 0.f};
        #pragma unroll
        for (int cc = 0; cc < 8; cc++) acc[cc] = MFMA16(a_cur, be[cc], acc[cc]);

        float p[4];
        #pragma unroll
        for (int i = 0; i < 4; i++) {
            const int edge = g * 4 + i;
            float s = 0.f;
            #pragma unroll
            for (int pg = 0; pg < 4; pg++) {
                f16x2 zz = *(const f16x2*)&myZ[edge * ZP3 + pg * 32 + 2 * l15];
                float v0 = (float)zz[0] + acc[2 * pg    ][i]; v0 = v0 > 0.f ? v0 : 0.f;
                float v1 = (float)zz[1] + acc[2 * pg + 1][i]; v1 = v1 > 0.f ? v1 : 0.f;
                s += v0 * w2p[pg].x + v1 * w2p[pg].y;
            }
            p[i] = s;
        }
        #pragma unroll
        for (int m = 1; m < 16; m <<= 1)
            #pragma unroll
            for (int i = 0; i < 4; i++) p[i] += __shfl_xor(p[i], m, 64);
        if (l15 == 0) {
            #pragma unroll
            for (int i = 0; i < 4; i++) {
                int pp = pbase + g * 4 + i;
                if (pp < E) tmp[pp] = p[i] + bv;     // sequential write, no RMW
            }
        }
        if (has_next) {
            stage_write();
            a_cur = a_next;
        }
    }
}

// ---------------- permute (GATHER form): out[e] = tmp[pos[e]] ----------------
__global__ void k_perm(const float* __restrict__ tmp, const int* __restrict__ pos,
                       float* __restrict__ out, int E) {
    int e = blockIdx.x * 256 + threadIdx.x;
    if (e < E) out[e] = tmp[pos[e]];
}

// ---------------- host launch ----------------
extern "C" void kernel_launch(void* const* d_in, const int* in_sizes, int n_in,
                              void* d_out, int out_size, void* d_ws, size_t ws_size,
                              hipStream_t stream) {
    const float* x   = (const float*)d_in[0];
    const void*  ei  = d_in[1];
    const float* ea  = (const float*)d_in[2];
    const float* Wl1 = (const float*)d_in[3];
    const float* Wr1 = (const float*)d_in[4];
    const float* b1  = (const float*)d_in[5];
    const float* Wl2 = (const float*)d_in[6];
    const float* Wr2 = (const float*)d_in[7];
    const float* b2  = (const float*)d_in[8];
    const float* Wm1 = (const float*)d_in[9];
    const float* bm1 = (const float*)d_in[10];
    const float* Wm2 = (const float*)d_in[11];
    const float* bm2 = (const float*)d_in[12];

    const int N = in_sizes[0] / 128;
    const int E = in_sizes[1] / 2;

    char* ws = (char*)d_ws;
    size_t off = 0;
    auto alloc = [&](size_t bytes) -> void* {
        void* p = ws + off;
        off = (off + bytes + 255) & ~(size_t)255;
        return p;
    };
    f16* z      = (f16*)alloc((size_t)N * 256 * 2);
    f16* xh     = z;
    f16* h1     = (f16*)alloc((size_t)N * 128 * 2);
    int2* pk2   = (int2*)alloc((size_t)E * 8);
    int* dstp   = (int*)alloc((size_t)E * 4);
    int* pos    = (int*)alloc((size_t)E * 4);
    float* tmp  = (float*)alloc((size_t)E * 4);
    int* deg    = (int*)alloc((size_t)N * 4);
    int* rowptr = (int*)alloc((size_t)(N + 1) * 4);
    int* cursor = (int*)alloc((size_t)N * 4);
    int* bsum   = (int*)alloc((size_t)1024 * 4);
    f16* w1f    = (f16*)alloc((size_t)8 * 8 * 64 * 8 * 2);
    f16* w2f    = (f16*)alloc((size_t)8 * 8 * 64 * 8 * 2);
    f16* zwf    = (f16*)alloc((size_t)4 * 16 * 64 * 8 * 2);
    f16* wef    = (f16*)alloc((size_t)8 * 64 * 8 * 2);
    int* flag   = (int*)alloc(4);
    if (off > ws_size) return;

    const int eb = (E + 255) / 256;
    const int nbk = (N + 1023) / 1024;
    const int rb64 = (N + 63) / 64;
    const int nb256 = (N + 255) / 256;

    k_detect<<<1, 64, 0, stream>>>((const long long*)ei, N, flag);
    hipMemsetAsync(deg, 0, (size_t)N * 4, stream);
    k_hist<<<eb, 256, 0, stream>>>(ei, E, flag, deg);
    const int xb = (N * 16 + 255) / 256;
    k_prep<<<xb + 50, 256, 0, stream>>>(x, Wl1, Wr1, Wl2, Wr2, Wm1,
                                        xh, w1f, w2f, zwf, wef, N);

    k_bsum<<<nbk, 256, 0, stream>>>(deg, N, bsum);
    k_bscan<<<1, 256, 0, stream>>>(bsum, nbk, rowptr + N);
    k_rowptr<<<nbk, 256, 0, stream>>>(deg, N, bsum, rowptr, cursor);
    k_dfill<<<nb256, 256, 0, stream>>>(rowptr, N, dstp);
    k_scatter<<<eb, 256, 0, stream>>>(ei, E, flag, cursor, pk2, pos);

    // layer 1: agg(xh) + gemm -> h1
    k_fuse<0><<<rb64, 256, 0, stream>>>(xh, rowptr, pk2, w1f, b1, nullptr, nullptr, h1, N);
    // layer 2: agg(h1) + gemm + z-gemm -> z
    k_fuse<1><<<rb64, 256, 0, stream>>>(h1, rowptr, pk2, w2f, b2, zwf, bm1, z, N);

    const int eg = 1792;
    const int nwaves = eg * 4;
    const int ntiles = (E + 15) / 16;
    const int e_iters = (ntiles + nwaves - 1) / nwaves;
    k_edge3<<<eg, 256, 0, stream>>>(z, ea, pk2, dstp, wef, Wm2, bm2,
                                    tmp, E, e_iters, nwaves);
    k_perm<<<eb, 256, 0, stream>>>(tmp, pos, (float*)d_out, E);
}

// Round 19
// 487.732 us; speedup vs baseline: 1.0873x; 1.0873x over previous
//
#include <hip/hip_runtime.h>

typedef _Float16 f16;
typedef _Float16 f16x2 __attribute__((ext_vector_type(2)));
typedef _Float16 f16x8 __attribute__((ext_vector_type(8)));
typedef float f32x4 __attribute__((ext_vector_type(4)));

#define MFMA16(a,b,c) __builtin_amdgcn_mfma_f32_16x16x32_f16((a),(b),(c),0,0,0)

// ---------------- index dtype detection (parallel) ----------------
__global__ void k_detect(const long long* ei, int n_nodes, int* flag) {
    long long v = ei[threadIdx.x];
    int bad = (v < 0 || v >= n_nodes);
    unsigned long long m = __ballot(bad);
    if (threadIdx.x == 0) *flag = (m == 0ULL);   // 1 => int64, 0 => int32
}

// histogram only (deg pre-zeroed); src/dst never materialized
__global__ void k_hist(const void* ei, int E, const int* __restrict__ flag,
                       int* __restrict__ deg) {
    int e = blockIdx.x * 256 + threadIdx.x;
    if (e >= E) return;
    int d;
    if (*flag) d = (int)((const long long*)ei)[(size_t)E + e];
    else       d = ((const int*)ei)[(size_t)E + e];
    atomicAdd(&deg[d], 1);
}

// ---------------- device helper: SAGE W frag ----------------
__device__ __forceinline__ void wfrag_body(const float* Wa, const float* Wb,
                                           f16* dst, int t) {
    int l = t & 63;
    int s = t >> 9;
    int k0 = s * 32 + (l >> 4) * 8;
    int j = ((t >> 6) & 7) * 16 + (l & 15);
    f16x8 h;
    #pragma unroll
    for (int e = 0; e < 8; e++) {
        int k = k0 + e;
        float v = (k < 128) ? Wa[k * 128 + j] : Wb[(k - 128) * 128 + j];
        h[e] = (f16)v;
    }
    *(f16x8*)(dst + (size_t)t * 8) = h;
}

// ---------------- fused prep: x2h + w1f + w2f + zwf + wef ----------------
__global__ void k_prep(const float* __restrict__ x,
                       const float* __restrict__ Wl1, const float* __restrict__ Wr1,
                       const float* __restrict__ Wl2, const float* __restrict__ Wr2,
                       const float* __restrict__ Wm1,
                       f16* __restrict__ xh, f16* __restrict__ w1f, f16* __restrict__ w2f,
                       f16* __restrict__ zwf, f16* __restrict__ wef, int N) {
    const int xb = (N * 16 + 255) / 256;
    int b = blockIdx.x;
    if (b < xb) {
        int i = (b * 256 + threadIdx.x) * 8;
        if (i >= N * 128) return;
        float4 a = *(const float4*)(x + i);
        float4 c = *(const float4*)(x + i + 4);
        f16x8 h;
        h[0] = (f16)a.x; h[1] = (f16)a.y; h[2] = (f16)a.z; h[3] = (f16)a.w;
        h[4] = (f16)c.x; h[5] = (f16)c.y; h[6] = (f16)c.z; h[7] = (f16)c.w;
        *(f16x8*)(xh + i) = h;
        return;
    }
    b -= xb;
    if (b < 16) { wfrag_body(Wl1, Wr1, w1f, b * 256 + threadIdx.x); return; }
    if (b < 32) { wfrag_body(Wl2, Wr2, w2f, (b - 16) * 256 + threadIdx.x); return; }
    if (b < 48) {                       // zwf
        int t = (b - 32) * 256 + threadIdx.x;
        int lane = t & 63, c = (t >> 6) & 15, s = t >> 10;
        int k0 = s * 32 + (lane >> 4) * 8;
        int j = c * 16 + (lane & 15);
        f16x8 h;
        #pragma unroll
        for (int e = 0; e < 8; e++) {
            int k = k0 + e;
            float v = (j < 128) ? Wm1[k * 128 + j] : Wm1[(128 + k) * 128 + (j - 128)];
            h[e] = (f16)v;
        }
        *(f16x8*)(zwf + (size_t)t * 8) = h;
        return;
    }
    {                                   // wef (paired-column order)
        int t = (b - 48) * 256 + threadIdx.x;
        if (t >= 8 * 64) return;
        int lane = t & 63, ct = t >> 6;
        int k0 = (lane >> 4) * 8;
        int j = (ct >> 1) * 32 + 2 * (lane & 15) + (ct & 1);
        f16x8 h;
        #pragma unroll
        for (int e = 0; e < 8; e++) {
            int k = k0 + e;
            h[e] = (k < 16) ? (f16)Wm1[(256 + k) * 128 + j] : (f16)0.0f;
        }
        *(f16x8*)(wef + (size_t)t * 8) = h;
    }
}

// ---------------- CSR build over N nodes ----------------
__global__ void k_bsum(const int* __restrict__ deg, int n, int* __restrict__ bsum) {
    __shared__ int ws[4];
    const int tid = threadIdx.x;
    int i = blockIdx.x * 1024 + tid * 4;
    int s = 0;
    if (i + 3 < n) {
        int4 d = *(const int4*)(deg + i);
        s = d.x + d.y + d.z + d.w;
    } else {
        #pragma unroll
        for (int j = 0; j < 4; j++) if (i + j < n) s += deg[i + j];
    }
    #pragma unroll
    for (int m = 1; m < 64; m <<= 1) s += __shfl_xor(s, m, 64);
    if ((tid & 63) == 0) ws[tid >> 6] = s;
    __syncthreads();
    if (tid == 0) bsum[blockIdx.x] = ws[0] + ws[1] + ws[2] + ws[3];
}

__global__ void k_bscan(int* __restrict__ bsum, int nb, int* __restrict__ rowptr_n) {
    __shared__ int wsum[4];
    const int tid = threadIdx.x, lane = tid & 63, wid = tid >> 6;
    int v = (tid < nb) ? bsum[tid] : 0;
    int inc = v;
    #pragma unroll
    for (int off = 1; off < 64; off <<= 1) {
        int u = __shfl_up(inc, off, 64);
        if (lane >= off) inc += u;
    }
    if (lane == 63) wsum[wid] = inc;
    __syncthreads();
    int woff = 0;
    for (int j = 0; j < wid; j++) woff += wsum[j];
    int excl = woff + inc - v;
    if (tid < nb) bsum[tid] = excl;
    if (tid == nb - 1) rowptr_n[0] = excl + v;
}

__global__ void k_rowptr(const int* __restrict__ deg, int n, const int* __restrict__ boff,
                         int* __restrict__ rowptr, int* __restrict__ cursor) {
    __shared__ int wsum[4];
    const int tid = threadIdx.x, lane = tid & 63, wid = tid >> 6;
    int i = blockIdx.x * 1024 + tid * 4;
    int d0 = 0, d1 = 0, d2 = 0, d3 = 0;
    if (i + 3 < n) {
        int4 d = *(const int4*)(deg + i);
        d0 = d.x; d1 = d.y; d2 = d.z; d3 = d.w;
    } else {
        if (i     < n) d0 = deg[i];
        if (i + 1 < n) d1 = deg[i + 1];
        if (i + 2 < n) d2 = deg[i + 2];
        if (i + 3 < n) d3 = deg[i + 3];
    }
    int s = d0 + d1 + d2 + d3;
    int inc = s;
    #pragma unroll
    for (int off = 1; off < 64; off <<= 1) {
        int u = __shfl_up(inc, off, 64);
        if (lane >= off) inc += u;
    }
    if (lane == 63) wsum[wid] = inc;
    __syncthreads();
    int woff = 0;
    for (int j = 0; j < wid; j++) woff += wsum[j];
    int excl = boff[blockIdx.x] + woff + inc - s;
    int e1 = excl + d0, e2 = e1 + d1, e3 = e2 + d2;
    if (i     < n) { rowptr[i]     = excl; cursor[i]     = excl; }
    if (i + 1 < n) { rowptr[i + 1] = e1;   cursor[i + 1] = e1; }
    if (i + 2 < n) { rowptr[i + 2] = e2;   cursor[i + 2] = e2; }
    if (i + 3 < n) { rowptr[i + 3] = e3;   cursor[i + 3] = e3; }
}

// scatter: reads ei directly; random writes col (4B) + pk2 (8B); pos sequential
__global__ void k_scatter(const void* ei, int E, const int* __restrict__ flag,
                          int* __restrict__ cursor, int* __restrict__ col,
                          int2* __restrict__ pk2, int* __restrict__ pos) {
    int e = blockIdx.x * 256 + threadIdx.x;
    if (e >= E) return;
    int s, d;
    if (*flag) {
        const long long* p = (const long long*)ei;
        s = (int)p[e];
        d = (int)p[(size_t)E + e];
    } else {
        const int* p = (const int*)ei;
        s = p[e];
        d = p[(size_t)E + e];
    }
    int p2 = atomicAdd(&cursor[d], 1);
    col[p2] = s;
    pk2[p2] = make_int2(e, d);
    pos[e] = p2;                         // sequential address, random value
}

// ---------------- fused layer kernel (R14-proven) ----------------
#define AP 136
template<int DO_Z>
__global__ __launch_bounds__(256, DO_Z ? 4 : 5) void k_fuse(
    const f16* __restrict__ tab,
    const int* __restrict__ rowptr, const int* __restrict__ col,
    const f16* __restrict__ Wf, const float* __restrict__ bias,
    const f16* __restrict__ zwf, const float* __restrict__ bm1,
    f16* __restrict__ out, int n_rows) {
    __shared__ __align__(16) f16 sA[64 * AP];
    const int tid = threadIdx.x, lane = tid & 63, w = tid >> 6;
    const int l15 = lane & 15, g = lane >> 4;
    const int base = blockIdx.x * 64;

    const int g16 = tid >> 4, c = tid & 15;
    #pragma unroll
    for (int rep = 0; rep < 4; rep++) {
        const int node = base + rep * 16 + g16;
        float acc[8] = {0.f, 0.f, 0.f, 0.f, 0.f, 0.f, 0.f, 0.f};
        int d = 1;
        if (node < n_rows) {
            const int s0 = rowptr[node], s1 = rowptr[node + 1];
            int k = s0;
            for (; k + 3 < s1; k += 4) {
                const int n0 = col[k], n1 = col[k + 1], n2 = col[k + 2], n3 = col[k + 3];
                f16x8 v0 = *(const f16x8*)(tab + (size_t)n0 * 128 + c * 8);
                f16x8 v1 = *(const f16x8*)(tab + (size_t)n1 * 128 + c * 8);
                f16x8 v2 = *(const f16x8*)(tab + (size_t)n2 * 128 + c * 8);
                f16x8 v3 = *(const f16x8*)(tab + (size_t)n3 * 128 + c * 8);
                #pragma unroll
                for (int j = 0; j < 8; j++)
                    acc[j] += ((float)v0[j] + (float)v1[j]) + ((float)v2[j] + (float)v3[j]);
            }
            for (; k < s1; ++k) {
                const int n0 = col[k];
                f16x8 v0 = *(const f16x8*)(tab + (size_t)n0 * 128 + c * 8);
                #pragma unroll
                for (int j = 0; j < 8; j++) acc[j] += (float)v0[j];
            }
            d = s1 - s0; if (d < 1) d = 1;
        }
        const float inv = 1.f / (float)d;
        f16x8 r;
        #pragma unroll
        for (int j = 0; j < 8; j++) r[j] = (f16)(acc[j] * inv);
        *(f16x8*)&sA[(rep * 16 + g16) * AP + c * 8] = r;
    }
    __syncthreads();

    const int c0 = (2 * w) * 16 + l15, c1 = c0 + 16;
    const float b0 = bias[c0], b1 = bias[c1];
    f32x4 acc[4][2];
    #pragma unroll
    for (int t = 0; t < 4; t++) {
        acc[t][0] = f32x4{b0, b0, b0, b0};
        acc[t][1] = f32x4{b1, b1, b1, b1};
    }
    #pragma unroll
    for (int s = 0; s < 8; s++) {
        f16x8 bf0 = *(const f16x8*)&Wf[((size_t)(s * 8 + 2 * w    ) * 64 + lane) * 8];
        f16x8 bf1 = *(const f16x8*)&Wf[((size_t)(s * 8 + 2 * w + 1) * 64 + lane) * 8];
        const int koff = (s & 3) * 32 + g * 8;
        #pragma unroll
        for (int t = 0; t < 4; t++) {
            f16x8 a;
            if (s < 4) {
                a = *(const f16x8*)&sA[(t * 16 + l15) * AP + koff];
            } else {
                int row = base + t * 16 + l15;
                if (row >= n_rows) row = n_rows - 1;
                a = *(const f16x8*)(tab + (size_t)row * 128 + koff);
            }
            acc[t][0] = MFMA16(a, bf0, acc[t][0]);
            acc[t][1] = MFMA16(a, bf1, acc[t][1]);
        }
    }

    if (DO_Z == 0) {
        #pragma unroll
        for (int t = 0; t < 4; t++) {
            #pragma unroll
            for (int i = 0; i < 4; i++) {
                int row = base + t * 16 + g * 4 + i;
                if (row < n_rows) {
                    float v0 = acc[t][0][i]; v0 = v0 > 0.f ? v0 : 0.f;
                    float v1 = acc[t][1][i]; v1 = v1 > 0.f ? v1 : 0.f;
                    out[(size_t)row * 128 + c0] = (f16)v0;
                    out[(size_t)row * 128 + c1] = (f16)v1;
                }
            }
        }
    } else {
        __syncthreads();
        #pragma unroll
        for (int t = 0; t < 4; t++) {
            #pragma unroll
            for (int i = 0; i < 4; i++) {
                const int rl = t * 16 + g * 4 + i;
                float v0 = acc[t][0][i]; v0 = v0 > 0.f ? v0 : 0.f;
                float v1 = acc[t][1][i]; v1 = v1 > 0.f ? v1 : 0.f;
                sA[rl * AP + c0] = (f16)v0;
                sA[rl * AP + c1] = (f16)v1;
            }
        }
        __syncthreads();
        #pragma unroll
        for (int half = 0; half < 2; half++) {
            const int j0 = (4 * w + 2 * half) * 16 + l15, j1 = j0 + 16;
            const float zb0 = (j0 >= 128) ? bm1[j0 - 128] : 0.0f;
            const float zb1 = (j1 >= 128) ? bm1[j1 - 128] : 0.0f;
            f32x4 zacc[4][2];
            #pragma unroll
            for (int t = 0; t < 4; t++) {
                zacc[t][0] = f32x4{zb0, zb0, zb0, zb0};
                zacc[t][1] = f32x4{zb1, zb1, zb1, zb1};
            }
            #pragma unroll
            for (int s = 0; s < 4; s++) {
                f16x8 wf0 = *(const f16x8*)&zwf[((size_t)(s * 16 + 4 * w + 2 * half    ) * 64 + lane) * 8];
                f16x8 wf1 = *(const f16x8*)&zwf[((size_t)(s * 16 + 4 * w + 2 * half + 1) * 64 + lane) * 8];
                const int koff = s * 32 + g * 8;
                #pragma unroll
                for (int t = 0; t < 4; t++) {
                    f16x8 a = *(const f16x8*)&sA[(t * 16 + l15) * AP + koff];
                    zacc[t][0] = MFMA16(a, wf0, zacc[t][0]);
                    zacc[t][1] = MFMA16(a, wf1, zacc[t][1]);
                }
            }
            #pragma unroll
            for (int t = 0; t < 4; t++) {
                #pragma unroll
                for (int i = 0; i < 4; i++) {
                    int row = base + t * 16 + g * 4 + i;
                    if (row < n_rows) {
                        out[(size_t)row * 256 + j0] = (f16)zacc[t][0][i];
                        out[(size_t)row * 256 + j1] = (f16)zacc[t][1][i];
                    }
                }
            }
        }
    }
}

// ---------------- edge kernel: CSR-position order, col+pk2 loads, sequential tmp ----------------
#define ZP3 136
__global__ __launch_bounds__(256, 4) void k_edge3(
    const f16* __restrict__ z, const float* __restrict__ ea,
    const int* __restrict__ colp, const int2* __restrict__ pk2,
    const f16* __restrict__ wef, const float* __restrict__ Wm2,
    const float* __restrict__ bm2, float* __restrict__ tmp,
    int E, int iters, int nwaves) {
    __shared__ __align__(16) f16 sZ[4][16 * ZP3];   // 4352 B per wave
    const int tid = threadIdx.x, lane = tid & 63, w = tid >> 6;
    const int l15 = lane & 15, g = lane >> 4;
    const int te = lane >> 2, sq = lane & 3;        // 4-lane team per edge
    const int gw = blockIdx.x * 4 + w;

    f16x8 be[8];
    #pragma unroll
    for (int cc = 0; cc < 8; cc++)
        be[cc] = *(const f16x8*)(wef + ((size_t)(cc * 64 + lane)) * 8);
    float2 w2p[4];
    #pragma unroll
    for (int pg = 0; pg < 4; pg++)
        w2p[pg] = *(const float2*)&Wm2[pg * 32 + 2 * l15];
    const float bv = bm2[0];

    f16* myZ = &sZ[w][0];

    f16x8 zs[4], zd[4];
    f16x8 a_cur, a_next;

    auto stage_load = [&](int pbase, f16x8* zsv, f16x8* zdv, f16x8& av) {
        int pr = pbase + te; if (pr > E - 1) pr = E - 1;
        const int is = colp[pr];
        const int2 v = pk2[pr];                      // (eid, dst)
        const int id = v.y;
        const f16* ps = z + (size_t)is * 256 + sq * 8;
        const f16* pd = z + (size_t)id * 256 + 128 + sq * 8;
        #pragma unroll
        for (int i = 0; i < 4; i++) {
            zsv[i] = *(const f16x8*)(ps + i * 32);   // line-coherent 16B chunks
            zdv[i] = *(const f16x8*)(pd + i * 32);
        }
        int pe = pbase + l15; if (pe > E - 1) pe = E - 1;
        f16x8 av_ = {};
        if (g < 2) {
            const int ee2 = pk2[pe].x;
            float4 e0 = *(const float4*)(ea + (size_t)ee2 * 16 + g * 8);
            float4 e1 = *(const float4*)(ea + (size_t)ee2 * 16 + g * 8 + 4);
            av_[0] = (f16)e0.x; av_[1] = (f16)e0.y; av_[2] = (f16)e0.z; av_[3] = (f16)e0.w;
            av_[4] = (f16)e1.x; av_[5] = (f16)e1.y; av_[6] = (f16)e1.z; av_[7] = (f16)e1.w;
        }
        av = av_;
    };
    auto stage_write = [&]() {
        f16* zp = myZ + te * ZP3 + sq * 8;
        #pragma unroll
        for (int i = 0; i < 4; i++) {
            f16x8 v = zs[i] + zd[i];            // v_pk_add_f16
            *(f16x8*)(zp + i * 32) = v;
        }
    };

    stage_load(gw * 16, zs, zd, a_cur);
    stage_write();

    for (int it = 0; it < iters; ++it) {
        const int pbase = (gw + it * nwaves) * 16;
        if (pbase >= E) break;
        const int nxt = (gw + (it + 1) * nwaves) * 16;
        const bool has_next = (it + 1 < iters) && (nxt < E);
        if (has_next) stage_load(nxt, zs, zd, a_next);

        f32x4 acc[8];
        #pragma unroll
        for (int cc = 0; cc < 8; cc++) acc[cc] = f32x4{0.f, 0.f, 0.f, 0.f};
        #pragma unroll
        for (int cc = 0; cc < 8; cc++) acc[cc] = MFMA16(a_cur, be[cc], acc[cc]);

        float p[4];
        #pragma unroll
        for (int i = 0; i < 4; i++) {
            const int edge = g * 4 + i;
            float s = 0.f;
            #pragma unroll
            for (int pg = 0; pg < 4; pg++) {
                f16x2 zz = *(const f16x2*)&myZ[edge * ZP3 + pg * 32 + 2 * l15];
                float v0 = (float)zz[0] + acc[2 * pg    ][i]; v0 = v0 > 0.f ? v0 : 0.f;
                float v1 = (float)zz[1] + acc[2 * pg + 1][i]; v1 = v1 > 0.f ? v1 : 0.f;
                s += v0 * w2p[pg].x + v1 * w2p[pg].y;
            }
            p[i] = s;
        }
        #pragma unroll
        for (int m = 1; m < 16; m <<= 1)
            #pragma unroll
            for (int i = 0; i < 4; i++) p[i] += __shfl_xor(p[i], m, 64);
        if (l15 == 0) {
            #pragma unroll
            for (int i = 0; i < 4; i++) {
                int pp = pbase + g * 4 + i;
                if (pp < E) tmp[pp] = p[i] + bv;     // sequential write, no RMW
            }
        }
        if (has_next) {
            stage_write();
            a_cur = a_next;
        }
    }
}

// ---------------- permute (GATHER form): out[e] = tmp[pos[e]] ----------------
__global__ void k_perm(const float* __restrict__ tmp, const int* __restrict__ pos,
                       float* __restrict__ out, int E) {
    int e = blockIdx.x * 256 + threadIdx.x;
    if (e < E) out[e] = tmp[pos[e]];
}

// ---------------- host launch ----------------
extern "C" void kernel_launch(void* const* d_in, const int* in_sizes, int n_in,
                              void* d_out, int out_size, void* d_ws, size_t ws_size,
                              hipStream_t stream) {
    const float* x   = (const float*)d_in[0];
    const void*  ei  = d_in[1];
    const float* ea  = (const float*)d_in[2];
    const float* Wl1 = (const float*)d_in[3];
    const float* Wr1 = (const float*)d_in[4];
    const float* b1  = (const float*)d_in[5];
    const float* Wl2 = (const float*)d_in[6];
    const float* Wr2 = (const float*)d_in[7];
    const float* b2  = (const float*)d_in[8];
    const float* Wm1 = (const float*)d_in[9];
    const float* bm1 = (const float*)d_in[10];
    const float* Wm2 = (const float*)d_in[11];
    const float* bm2 = (const float*)d_in[12];

    const int N = in_sizes[0] / 128;
    const int E = in_sizes[1] / 2;

    char* ws = (char*)d_ws;
    size_t off = 0;
    auto alloc = [&](size_t bytes) -> void* {
        void* p = ws + off;
        off = (off + bytes + 255) & ~(size_t)255;
        return p;
    };
    f16* z      = (f16*)alloc((size_t)N * 256 * 2);
    f16* xh     = z;
    f16* h1     = (f16*)alloc((size_t)N * 128 * 2);
    int* col    = (int*)alloc((size_t)E * 4);
    int2* pk2   = (int2*)alloc((size_t)E * 8);
    int* pos    = (int*)alloc((size_t)E * 4);
    float* tmp  = (float*)alloc((size_t)E * 4);
    int* deg    = (int*)alloc((size_t)N * 4);
    int* rowptr = (int*)alloc((size_t)(N + 1) * 4);
    int* cursor = (int*)alloc((size_t)N * 4);
    int* bsum   = (int*)alloc((size_t)1024 * 4);
    f16* w1f    = (f16*)alloc((size_t)8 * 8 * 64 * 8 * 2);
    f16* w2f    = (f16*)alloc((size_t)8 * 8 * 64 * 8 * 2);
    f16* zwf    = (f16*)alloc((size_t)4 * 16 * 64 * 8 * 2);
    f16* wef    = (f16*)alloc((size_t)8 * 64 * 8 * 2);
    int* flag   = (int*)alloc(4);
    if (off > ws_size) return;

    const int eb = (E + 255) / 256;
    const int nbk = (N + 1023) / 1024;
    const int rb64 = (N + 63) / 64;

    k_detect<<<1, 64, 0, stream>>>((const long long*)ei, N, flag);
    hipMemsetAsync(deg, 0, (size_t)N * 4, stream);
    k_hist<<<eb, 256, 0, stream>>>(ei, E, flag, deg);
    const int xb = (N * 16 + 255) / 256;
    k_prep<<<xb + 50, 256, 0, stream>>>(x, Wl1, Wr1, Wl2, Wr2, Wm1,
                                        xh, w1f, w2f, zwf, wef, N);

    k_bsum<<<nbk, 256, 0, stream>>>(deg, N, bsum);
    k_bscan<<<1, 256, 0, stream>>>(bsum, nbk, rowptr + N);
    k_rowptr<<<nbk, 256, 0, stream>>>(deg, N, bsum, rowptr, cursor);
    k_scatter<<<eb, 256, 0, stream>>>(ei, E, flag, cursor, col, pk2, pos);

    // layer 1: agg(xh) + gemm -> h1
    k_fuse<0><<<rb64, 256, 0, stream>>>(xh, rowptr, col, w1f, b1, nullptr, nullptr, h1, N);
    // layer 2: agg(h1) + gemm + z-gemm -> z
    k_fuse<1><<<rb64, 256, 0, stream>>>(h1, rowptr, col, w2f, b2, zwf, bm1, z, N);

    const int eg = 1792;
    const int nwaves = eg * 4;
    const int ntiles = (E + 15) / 16;
    const int e_iters = (ntiles + nwaves - 1) / nwaves;
    k_edge3<<<eg, 256, 0, stream>>>(z, ea, col, pk2, wef, Wm2, bm2,
                                    tmp, E, e_iters, nwaves);
    k_perm<<<eb, 256, 0, stream>>>(tmp, pos, (float*)d_out, E);
}